// Round 1
// 322.109 us; speedup vs baseline: 1.2578x; 1.2578x over previous
//
#include <hip/hip_runtime.h>

#define NN 100000
#define NE 1600000
#define DD 128
#define BN_EPS 1e-5f

#define NWIN 782                       // ceil(NN/128) 128-node windows
#define EPB 8192                       // edges per block (scatter)
#define NBLK ((NE + EPB - 1) / EPB)    // 196
#define CAP 3072                       // per-window slot capacity (mean 2046, sigma ~45)

typedef __attribute__((ext_vector_type(8))) short short8;
typedef __attribute__((ext_vector_type(4))) float floatx4;

__device__ __forceinline__ unsigned short f2bf(float f) {
    union { float f; unsigned u; } v; v.f = f;
    return (unsigned short)((v.u + 0x7FFFu + ((v.u >> 16) & 1u)) >> 16);
}
__device__ __forceinline__ float bf2f(unsigned short u) {
    union { unsigned u; float f; } v; v.u = ((unsigned)u) << 16;
    return v.f;
}

// ---------------------------------------------------------------------------
// Kernel 0: zero stats + window counters; W1,W2 -> bf16 transposed [n][k];
// optional h->bf16 copy.
// ---------------------------------------------------------------------------
__global__ __launch_bounds__(256) void prep_kernel(
    float* __restrict__ stats, int* __restrict__ wcnt,
    const float* __restrict__ W1, const float* __restrict__ W2,
    unsigned short* __restrict__ W1t, unsigned short* __restrict__ W2t,
    const float* __restrict__ h, unsigned short* __restrict__ hb, int do_hb)
{
    int tid0 = blockIdx.x * blockDim.x + threadIdx.x;
    int stride = gridDim.x * blockDim.x;
    if (tid0 < 2 * DD) stats[tid0] = 0.0f;
    if (tid0 < NWIN) wcnt[tid0] = 0;
    for (int i = tid0; i < DD * DD; i += stride) {
        int n = i >> 7, k = i & 127;
        W1t[i] = f2bf(W1[k * DD + n]);
        W2t[i] = f2bf(W2[k * DD + n]);
    }
    if (do_hb) {
        const float4* h4 = (const float4*)h;
        ushort4* hb4 = (ushort4*)hb;
        for (int i = tid0; i < NN * (DD / 4); i += stride) {
            float4 v = h4[i];
            ushort4 o;
            o.x = f2bf(v.x); o.y = f2bf(v.y); o.z = f2bf(v.z); o.w = f2bf(v.w);
            hb4[i] = o;
        }
    }
}

// ---------------------------------------------------------------------------
// P1: single-pass window scatter with atomic chunk reservation.
// Each block LDS-histograms its 8192 edges over the 782 windows, reserves a
// contiguous chunk per window via one global atomicAdd per nonzero bin, then
// scatters entries (src<<7 | dst&127) into the window's fixed CAP region.
// Replaces the old histogram + 3-kernel global scan + scatter (5 kernels -> 1).
// Ordering within a window becomes nondeterministic but segment-sum in f32 at
// absmax tolerance is order-insensitive at this scale.
// ---------------------------------------------------------------------------
__global__ __launch_bounds__(256) void wscatter_kernel(
    const int* __restrict__ src, const int* __restrict__ dst,
    int* __restrict__ wcnt, int* __restrict__ estage)
{
    __shared__ int bins[NWIN];
    int blk = blockIdx.x, t = threadIdx.x;
    for (int j = t; j < NWIN; j += 256) bins[j] = 0;
    __syncthreads();
    int base = blk * EPB;
    int cnt = min(EPB, NE - base);
    for (int i = t; i < cnt; i += 256)
        atomicAdd(&bins[dst[base + i] >> 7], 1);
    __syncthreads();
    for (int j = t; j < NWIN; j += 256) {
        int c = bins[j];
        int b = (c > 0) ? atomicAdd(&wcnt[j], c) : 0;
        bins[j] = j * CAP + b;   // becomes this block's running cursor
    }
    __syncthreads();
    for (int i = t; i < cnt; i += 256) {
        int e = base + i;
        int d = dst[e];
        int pos = atomicAdd(&bins[d >> 7], 1);
        estage[pos] = (src[e] << 7) | (d & 127);
    }
}

// ---------------------------------------------------------------------------
// P2: per-window in-place permute into per-node CSR order, via LDS staging.
// Derives per-node counts/offsets locally, writes off2[node] = {beg, end}
// (absolute indices into the window-strided buffer).
// ---------------------------------------------------------------------------
__global__ __launch_bounds__(256) void wpermute_kernel(
    const int* __restrict__ wcnt, int* __restrict__ estage,
    int2* __restrict__ off2)
{
    __shared__ int ew[CAP];
    __shared__ int cnt[128];
    __shared__ int part[128];
    __shared__ int cur[128];
    int b = blockIdx.x, t = threadIdx.x;
    int wbase = b * CAP;
    int n = min(wcnt[b], CAP);
    if (t < 128) cnt[t] = 0;
    __syncthreads();
    for (int i = t; i < n; i += 256) {
        int e = estage[wbase + i];
        ew[i] = e;
        atomicAdd(&cnt[e & 127], 1);
    }
    __syncthreads();
    if (t < 128) part[t] = cnt[t];
    __syncthreads();
#pragma unroll
    for (int ofs = 1; ofs < 128; ofs <<= 1) {
        int u = (t < 128 && t >= ofs) ? part[t - ofs] : 0;
        __syncthreads();
        if (t < 128) part[t] += u;
        __syncthreads();
    }
    if (t < 128) {
        int excl = part[t] - cnt[t];
        cur[t] = wbase + excl;
        int node = (b << 7) + t;
        if (node < NN) off2[node] = make_int2(wbase + excl, wbase + excl + cnt[t]);
    }
    __syncthreads();
    for (int i = t; i < n; i += 256) {
        int e = ew[i];
        int pos = atomicAdd(&cur[e & 127], 1);
        estage[pos] = e >> 7;   // in-place: reads already staged in LDS
    }
}

// ---------------------------------------------------------------------------
// Kernel 3a: gather-sum, bf16 h copy. 16 lanes/node (16B/lane, full coalesced
// 256B row), unroll-4 -> 16 row-loads in flight per wave (4x the old kernel)
// to lift the latency-bound plateau.
// ---------------------------------------------------------------------------
__global__ __launch_bounds__(256) void gather_bf16_kernel(
    const float* __restrict__ h, const unsigned short* __restrict__ hb,
    const float* __restrict__ eps, const int2* __restrict__ off2,
    const int* __restrict__ src_sorted, unsigned short* __restrict__ xb)
{
    int node = blockIdx.x * 16 + (threadIdx.x >> 4);
    if (node >= NN) return;
    int c8 = threadIdx.x & 15;
    const float s = 1.0f + eps[0];
    const float4* h4 = (const float4*)h;
    float4 a0 = h4[node * 32 + c8 * 2];
    float4 a1 = h4[node * 32 + c8 * 2 + 1];
    float acc[8] = {s * a0.x, s * a0.y, s * a0.z, s * a0.w,
                    s * a1.x, s * a1.y, s * a1.z, s * a1.w};
    int2 oo = off2[node];
    int e = oo.x, eend = oo.y;
    const short8* hb8 = (const short8*)hb;
    for (; e + 3 < eend; e += 4) {
        int s0 = src_sorted[e],     s1 = src_sorted[e + 1];
        int s2 = src_sorted[e + 2], s3 = src_sorted[e + 3];
        short8 v0 = hb8[s0 * 16 + c8];
        short8 v1 = hb8[s1 * 16 + c8];
        short8 v2 = hb8[s2 * 16 + c8];
        short8 v3 = hb8[s3 * 16 + c8];
#pragma unroll
        for (int j = 0; j < 8; ++j) {
            float t0 = bf2f((unsigned short)v0[j]) + bf2f((unsigned short)v1[j]);
            float t1 = bf2f((unsigned short)v2[j]) + bf2f((unsigned short)v3[j]);
            acc[j] += t0 + t1;
        }
    }
    for (; e < eend; ++e) {
        short8 v0 = hb8[src_sorted[e] * 16 + c8];
#pragma unroll
        for (int j = 0; j < 8; ++j) acc[j] += bf2f((unsigned short)v0[j]);
    }
    short8 o;
#pragma unroll
    for (int j = 0; j < 8; ++j) o[j] = (short)f2bf(acc[j]);
    ((short8*)xb)[node * 16 + c8] = o;
}

// ---------------------------------------------------------------------------
// Kernel 3b: gather-sum, fp32 h (fallback if ws too small for hb). Same
// 16-lane structure, unroll-2 (rows are 512B so 8 loads in flight/wave).
// ---------------------------------------------------------------------------
__global__ __launch_bounds__(256) void gather_f32_kernel(
    const float* __restrict__ h, const float* __restrict__ eps,
    const int2* __restrict__ off2, const int* __restrict__ src_sorted,
    unsigned short* __restrict__ xb)
{
    int node = blockIdx.x * 16 + (threadIdx.x >> 4);
    if (node >= NN) return;
    int c8 = threadIdx.x & 15;
    const float4* h4 = (const float4*)h;
    const float s = 1.0f + eps[0];
    float4 a0 = h4[node * 32 + c8 * 2];
    float4 a1 = h4[node * 32 + c8 * 2 + 1];
    float acc[8] = {s * a0.x, s * a0.y, s * a0.z, s * a0.w,
                    s * a1.x, s * a1.y, s * a1.z, s * a1.w};
    int2 oo = off2[node];
    int e = oo.x, eend = oo.y;
    for (; e + 1 < eend; e += 2) {
        int s0 = src_sorted[e], s1 = src_sorted[e + 1];
        float4 u0 = h4[s0 * 32 + c8 * 2], u1 = h4[s0 * 32 + c8 * 2 + 1];
        float4 w0 = h4[s1 * 32 + c8 * 2], w1 = h4[s1 * 32 + c8 * 2 + 1];
        acc[0] += u0.x + w0.x; acc[1] += u0.y + w0.y;
        acc[2] += u0.z + w0.z; acc[3] += u0.w + w0.w;
        acc[4] += u1.x + w1.x; acc[5] += u1.y + w1.y;
        acc[6] += u1.z + w1.z; acc[7] += u1.w + w1.w;
    }
    if (e < eend) {
        int s0 = src_sorted[e];
        float4 u0 = h4[s0 * 32 + c8 * 2], u1 = h4[s0 * 32 + c8 * 2 + 1];
        acc[0] += u0.x; acc[1] += u0.y; acc[2] += u0.z; acc[3] += u0.w;
        acc[4] += u1.x; acc[5] += u1.y; acc[6] += u1.z; acc[7] += u1.w;
    }
    short8 o;
#pragma unroll
    for (int j = 0; j < 8; ++j) o[j] = (short)f2bf(acc[j]);
    ((short8*)xb)[node * 16 + c8] = o;
}

// ---------------------------------------------------------------------------
// Kernel 4: fused MLP: Y = relu(X@W1+b1)@W2 + b2, bf16 MFMA, Y1 never leaves
// LDS. Epilogue accumulates BN column sums/sumsq via per-block reduction +
// one atomicAdd per (col,stat). Saves the 51MB Y1 round-trip + 25.6MB stats
// pass + 2 launches.
// ---------------------------------------------------------------------------
__global__ __launch_bounds__(256) void mlp_fused_kernel(
    const unsigned short* __restrict__ X,
    const unsigned short* __restrict__ W1t, const unsigned short* __restrict__ W2t,
    const float* __restrict__ b1, const float* __restrict__ b2,
    unsigned short* __restrict__ Y, float* __restrict__ stats)
{
    extern __shared__ char smem[];
    unsigned short* wl = (unsigned short*)smem;            // [128][136] bf16 (W1 then W2)
    unsigned short* xl = (unsigned short*)(smem + 34816);  // [64][136] bf16 (X -> Y1 -> Y2)

    const int tid = threadIdx.x;
    const int r0 = blockIdx.x * 64;
    const int lane = tid & 63;
    const int wv = tid >> 6;
    const int m = lane & 15;
    const int hi = lane >> 4;

    // stage W1 + X
    const short8* W18 = (const short8*)W1t;
#pragma unroll
    for (int l = 0; l < 8; ++l) {
        int idx = tid + l * 256;
        int n = idx >> 4, c = idx & 15;
        *(short8*)&wl[n * 136 + c * 8] = W18[idx];
    }
    const short8* X8 = (const short8*)X;
#pragma unroll
    for (int l = 0; l < 4; ++l) {
        int idx = tid + l * 256;
        int row = idx >> 4, c = idx & 15;
        int g = r0 + row;
        short8 v = {0, 0, 0, 0, 0, 0, 0, 0};
        if (g < NN) v = X8[g * 16 + c];
        *(short8*)&xl[row * 136 + c * 8] = v;
    }
    __syncthreads();

    floatx4 acc[8];
#pragma unroll
    for (int i = 0; i < 8; ++i) acc[i] = (floatx4){0.f, 0.f, 0.f, 0.f};
#pragma unroll
    for (int kc = 0; kc < 4; ++kc) {
        short8 a = *(const short8*)&xl[(wv * 16 + m) * 136 + kc * 32 + hi * 8];
#pragma unroll
        for (int nt = 0; nt < 8; ++nt) {
            short8 b = *(const short8*)&wl[(nt * 16 + m) * 136 + kc * 32 + hi * 8];
            acc[nt] = __builtin_amdgcn_mfma_f32_16x16x32_bf16(a, b, acc[nt], 0, 0, 0);
        }
    }
    __syncthreads();  // all reads of wl (W1) and xl (X) done

    // Y1 = relu(acc + b1) -> xl ; stage W2 -> wl
#pragma unroll
    for (int nt = 0; nt < 8; ++nt) {
        float bv = b1[nt * 16 + m];
#pragma unroll
        for (int r = 0; r < 4; ++r) {
            float v = fmaxf(acc[nt][r] + bv, 0.f);
            xl[(wv * 16 + hi * 4 + r) * 136 + nt * 16 + m] = f2bf(v);
        }
    }
    const short8* W28 = (const short8*)W2t;
#pragma unroll
    for (int l = 0; l < 8; ++l) {
        int idx = tid + l * 256;
        int n = idx >> 4, c = idx & 15;
        *(short8*)&wl[n * 136 + c * 8] = W28[idx];
    }
    __syncthreads();

    // GEMM2: Y2 = Y1 @ W2 + b2
#pragma unroll
    for (int i = 0; i < 8; ++i) acc[i] = (floatx4){0.f, 0.f, 0.f, 0.f};
#pragma unroll
    for (int kc = 0; kc < 4; ++kc) {
        short8 a = *(const short8*)&xl[(wv * 16 + m) * 136 + kc * 32 + hi * 8];
#pragma unroll
        for (int nt = 0; nt < 8; ++nt) {
            short8 b = *(const short8*)&wl[(nt * 16 + m) * 136 + kc * 32 + hi * 8];
            acc[nt] = __builtin_amdgcn_mfma_f32_16x16x32_bf16(a, b, acc[nt], 0, 0, 0);
        }
    }
    __syncthreads();

#pragma unroll
    for (int nt = 0; nt < 8; ++nt) {
        float bv = b2[nt * 16 + m];
#pragma unroll
        for (int r = 0; r < 4; ++r) {
            float v = acc[nt][r] + bv;
            xl[(wv * 16 + hi * 4 + r) * 136 + nt * 16 + m] = f2bf(v);
        }
    }
    __syncthreads();

    // store Y2
#pragma unroll
    for (int l = 0; l < 4; ++l) {
        int idx = tid + l * 256;
        int row = idx >> 4, c = idx & 15;
        int g = r0 + row;
        if (g < NN)
            ((short8*)Y)[g * 16 + c] = *(const short8*)&xl[row * 136 + c * 8];
    }

    // BN partial stats from the resident C tile (valid rows only)
    int col = tid & 127, half = tid >> 7;
    int rlim = min(64, NN - r0);
    int rbeg = half * 32, rend = min(rbeg + 32, rlim);
    float s = 0.f, q = 0.f;
    for (int r = rbeg; r < rend; ++r) {
        float v = bf2f(xl[r * 136 + col]);
        s += v; q += v * v;
    }
    float* red = (float*)wl;  // wl no longer needed
    red[tid] = s;
    red[256 + tid] = q;
    __syncthreads();
    if (half == 0) {
        atomicAdd(&stats[col],      red[col] + red[128 + col]);
        atomicAdd(&stats[DD + col], red[256 + col] + red[256 + 128 + col]);
    }
}

// ---------------------------------------------------------------------------
// Kernel 5: out = h + relu((Y - mean) * rsqrt(var+eps) * gamma + beta)
// ---------------------------------------------------------------------------
__global__ __launch_bounds__(256) void bn_final_kernel(
    const unsigned short* __restrict__ Y, const float* __restrict__ h,
    const float* __restrict__ gamma, const float* __restrict__ beta,
    const float* __restrict__ stats, float* __restrict__ out)
{
    const float invN = 1.0f / (float)NN;
    const ushort4* Y4 = (const ushort4*)Y;
    const float4* H4 = (const float4*)h;
    float4* O4 = (float4*)out;
    const int total = NN * (DD / 4);
    for (int i = blockIdx.x * blockDim.x + threadIdx.x; i < total;
         i += gridDim.x * blockDim.x) {
        int cg = i & 31;
        int c = cg << 2;
        ushort4 u = Y4[i];
        float4 hv = H4[i];
        float4 g = ((const float4*)gamma)[cg];
        float4 bt = ((const float4*)beta)[cg];

        float m0 = stats[c + 0] * invN, m1 = stats[c + 1] * invN;
        float m2 = stats[c + 2] * invN, m3 = stats[c + 3] * invN;
        float v0 = stats[DD + c + 0] * invN - m0 * m0;
        float v1 = stats[DD + c + 1] * invN - m1 * m1;
        float v2 = stats[DD + c + 2] * invN - m2 * m2;
        float v3 = stats[DD + c + 3] * invN - m3 * m3;

        float4 r;
        r.x = hv.x + fmaxf((bf2f(u.x) - m0) * rsqrtf(v0 + BN_EPS) * g.x + bt.x, 0.f);
        r.y = hv.y + fmaxf((bf2f(u.y) - m1) * rsqrtf(v1 + BN_EPS) * g.y + bt.y, 0.f);
        r.z = hv.z + fmaxf((bf2f(u.z) - m2) * rsqrtf(v2 + BN_EPS) * g.z + bt.z, 0.f);
        r.w = hv.w + fmaxf((bf2f(u.w) - m3) * rsqrtf(v3 + BN_EPS) * g.w + bt.w, 0.f);
        O4[i] = r;
    }
}

// ---------------------------------------------------------------------------
extern "C" void kernel_launch(void* const* d_in, const int* in_sizes, int n_in,
                              void* d_out, int out_size, void* d_ws, size_t ws_size,
                              hipStream_t stream)
{
    const float* h     = (const float*)d_in[0];
    const int*   src   = (const int*)d_in[1];
    const int*   dst   = (const int*)d_in[2];
    const float* eps   = (const float*)d_in[3];
    const float* W1    = (const float*)d_in[4];
    const float* b1    = (const float*)d_in[5];
    const float* W2    = (const float*)d_in[6];
    const float* b2    = (const float*)d_in[7];
    const float* gamma = (const float*)d_in[8];
    const float* beta  = (const float*)d_in[9];
    float* out = (float*)d_out;

    // workspace layout (16B-aligned segments). hb is last so the f32-gather
    // fallback kicks in first if ws is tight.
    char* w = (char*)d_ws;
    size_t o = 0;
    int2* off2      = (int2*)(w + o); o += (size_t)NN * 8;           // 800000
    float* stats    = (float*)(w + o); o += 256 * 4;
    unsigned short* W1t = (unsigned short*)(w + o); o += (size_t)DD * DD * 2;
    unsigned short* W2t = (unsigned short*)(w + o); o += (size_t)DD * DD * 2;
    int* wcnt       = (int*)(w + o); o += 1024 * 4;                  // NWIN used
    int* estage     = (int*)(w + o); o += (size_t)NWIN * CAP * 4;    // 9.6 MB
    unsigned short* xb  = (unsigned short*)(w + o); o += (size_t)NN * DD * 2;
    unsigned short* hb  = (unsigned short*)(w + o); o += (size_t)NN * DD * 2;
    const int use_hb = (ws_size >= o) ? 1 : 0;  // launch-constant

    // 0. zero stats/wcnt, bf16 transposed weights (+ bf16 h copy)
    prep_kernel<<<512, 256, 0, stream>>>(stats, wcnt, W1, W2, W1t, W2t, h, hb, use_hb);

    // 1. single-pass window scatter (atomic chunk reservation)
    wscatter_kernel<<<NBLK, 256, 0, stream>>>(src, dst, wcnt, estage);

    // 2. per-window in-place permute -> CSR order + off2[]
    wpermute_kernel<<<NWIN, 256, 0, stream>>>(wcnt, estage, off2);

    // 3. xb = bf16((1+eps)*h + neighbor-sum)
    if (use_hb)
        gather_bf16_kernel<<<(NN + 15) / 16, 256, 0, stream>>>(h, hb, eps, off2, estage, xb);
    else
        gather_f32_kernel<<<(NN + 15) / 16, 256, 0, stream>>>(h, eps, off2, estage, xb);

    // 4. fused 2-layer MLP + BN stats
    int gemm_blocks = (NN + 63) / 64;  // 1563
    size_t gemm_lds = 34816 + 17408;   // 52224 B
    mlp_fused_kernel<<<gemm_blocks, 256, gemm_lds, stream>>>(xb, W1t, W2t, b1, b2, xb, stats);

    // 5. out = h + relu(BN(y2))
    bn_final_kernel<<<1024, 256, 0, stream>>>(xb, h, gamma, beta, stats, out);
}

// Round 2
// 298.234 us; speedup vs baseline: 1.3585x; 1.0801x over previous
//
#include <hip/hip_runtime.h>

#define NN 100000
#define NE 1600000
#define DD 128
#define BN_EPS 1e-5f

#define NWIN 782                       // ceil(NN/128) 128-node windows
#define EPB 8192                       // edges per scatter block
#define NBLK ((NE + EPB - 1) / EPB)    // 196 scatter blocks
#define CAP 3072                       // per-window slot capacity (mean 2046, sigma ~45)
#define PREPBLKS 316                   // prep role blocks in fused kernel
#define GRID_PS (NBLK + PREPBLKS)      // 512
#define BN_BLOCKS 1024

typedef __attribute__((ext_vector_type(8))) short short8;
typedef __attribute__((ext_vector_type(4))) float floatx4;

__device__ __forceinline__ unsigned short f2bf(float f) {
    union { float f; unsigned u; } v; v.f = f;
    return (unsigned short)((v.u + 0x7FFFu + ((v.u >> 16) & 1u)) >> 16);
}
__device__ __forceinline__ float bf2f(unsigned short u) {
    union { unsigned u; float f; } v; v.u = ((unsigned)u) << 16;
    return v.f;
}

// ---------------------------------------------------------------------------
// Kernel 1 (fused): blocks [0,196) = window scatter with atomic chunk
// reservation; blocks [196,512) = prep (zero stats, W->bf16 transpose,
// h->bf16 copy). The two roles have disjoint data and co-schedule streaming
// (prep) with LDS-atomic/random-write work (scatter) across CUs.
// wcnt must be zeroed by the preceding hipMemsetAsync.
// ---------------------------------------------------------------------------
__global__ __launch_bounds__(256) void prep_scatter_kernel(
    float* __restrict__ stats,
    const float* __restrict__ W1, const float* __restrict__ W2,
    unsigned short* __restrict__ W1t, unsigned short* __restrict__ W2t,
    const float* __restrict__ h, unsigned short* __restrict__ hb, int do_hb,
    const int* __restrict__ src, const int* __restrict__ dst,
    int* __restrict__ wcnt, int* __restrict__ estage)
{
    __shared__ int bins[NWIN];    // 3128 B
    __shared__ int dstl[EPB];     // 32768 B: cache dst to avoid 2nd HBM read
    int t = threadIdx.x;

    if (blockIdx.x < NBLK) {
        // ---- scatter role ----
        int blk = blockIdx.x;
        for (int j = t; j < NWIN; j += 256) bins[j] = 0;
        __syncthreads();
        int base = blk * EPB;
        int cnt = min(EPB, NE - base);
        for (int i = t; i < cnt; i += 256) {
            int d = dst[base + i];
            dstl[i] = d;
            atomicAdd(&bins[d >> 7], 1);
        }
        __syncthreads();
        for (int j = t; j < NWIN; j += 256) {
            int c = bins[j];
            int b = (c > 0) ? atomicAdd(&wcnt[j], c) : 0;
            bins[j] = j * CAP + b;   // running cursor for this block
        }
        __syncthreads();
        for (int i = t; i < cnt; i += 256) {
            int d = dstl[i];
            int pos = atomicAdd(&bins[d >> 7], 1);
            estage[pos] = (src[base + i] << 7) | (d & 127);
        }
    } else {
        // ---- prep role ----
        int tid0 = (blockIdx.x - NBLK) * 256 + t;
        int stride = PREPBLKS * 256;
        if (tid0 < 2 * DD) stats[tid0] = 0.0f;
        for (int i = tid0; i < DD * DD; i += stride) {
            int n = i >> 7, k = i & 127;
            W1t[i] = f2bf(W1[k * DD + n]);
            W2t[i] = f2bf(W2[k * DD + n]);
        }
        if (do_hb) {
            const float4* h4 = (const float4*)h;
            ushort4* hb4 = (ushort4*)hb;
            for (int i = tid0; i < NN * (DD / 4); i += stride) {
                float4 v = h4[i];
                ushort4 o;
                o.x = f2bf(v.x); o.y = f2bf(v.y); o.z = f2bf(v.z); o.w = f2bf(v.w);
                hb4[i] = o;
            }
        }
    }
}

// ---------------------------------------------------------------------------
// Kernel 2 (fused): per-window CSR permute IN LDS + gather-sum.
// One block per window (512 threads = 8 waves). The window's edge list is
// staged into LDS, counted/scanned/permuted per node there (no estage
// round-trip, no off2 buffer), then the gather reads index lists from LDS
// and rows from hb (bf16, HB=1) or h (fp32 fallback).
// ---------------------------------------------------------------------------
template <bool HB>
__global__ __launch_bounds__(512) void permgather_kernel(
    const float* __restrict__ h, const unsigned short* __restrict__ hb,
    const float* __restrict__ eps, const int* __restrict__ wcnt,
    const int* __restrict__ estage, unsigned short* __restrict__ xb)
{
    __shared__ int ew[CAP];       // raw entries (src<<7 | dstlane)
    __shared__ int es[CAP];       // permuted src indices, CSR by node
    __shared__ int cnt[128];
    __shared__ int scn[128];
    __shared__ int begS[128];
    __shared__ int endS[128];
    __shared__ int cur[128];

    int b = blockIdx.x, t = threadIdx.x;
    if (t < 128) cnt[t] = 0;
    __syncthreads();

    int n = min(wcnt[b], CAP);
    int wbase = b * CAP;
    for (int i = t; i < n; i += 512) {
        int e = estage[wbase + i];
        ew[i] = e;
        atomicAdd(&cnt[e & 127], 1);
    }
    __syncthreads();

    if (t < 128) scn[t] = cnt[t];
    __syncthreads();
#pragma unroll
    for (int ofs = 1; ofs < 128; ofs <<= 1) {
        int u = (t < 128 && t >= ofs) ? scn[t - ofs] : 0;
        __syncthreads();
        if (t < 128) scn[t] += u;
        __syncthreads();
    }
    if (t < 128) {
        int excl = scn[t] - cnt[t];
        begS[t] = excl;
        endS[t] = excl + cnt[t];
        cur[t] = excl;
    }
    __syncthreads();

    for (int i = t; i < n; i += 512) {
        int e = ew[i];
        int pos = atomicAdd(&cur[e & 127], 1);
        es[pos] = e >> 7;
    }
    __syncthreads();

    // ---- gather phase: 32 nodes per pass, 16 lanes/node ----
    const float sE = 1.0f + eps[0];
    const float4* h4 = (const float4*)h;
    const short8* hb8 = (const short8*)hb;
    int c8 = t & 15;
#pragma unroll
    for (int pass = 0; pass < 4; ++pass) {
        int nl = pass * 32 + (t >> 4);
        int node = (b << 7) + nl;
        if (node >= NN) continue;
        float4 a0 = h4[node * 32 + c8 * 2];
        float4 a1 = h4[node * 32 + c8 * 2 + 1];
        float acc[8] = {sE * a0.x, sE * a0.y, sE * a0.z, sE * a0.w,
                        sE * a1.x, sE * a1.y, sE * a1.z, sE * a1.w};
        int e = begS[nl], eend = endS[nl];
        if (HB) {
            for (; e + 3 < eend; e += 4) {
                int s0 = es[e], s1 = es[e + 1], s2 = es[e + 2], s3 = es[e + 3];
                short8 v0 = hb8[s0 * 16 + c8];
                short8 v1 = hb8[s1 * 16 + c8];
                short8 v2 = hb8[s2 * 16 + c8];
                short8 v3 = hb8[s3 * 16 + c8];
#pragma unroll
                for (int j = 0; j < 8; ++j) {
                    float t0 = bf2f((unsigned short)v0[j]) + bf2f((unsigned short)v1[j]);
                    float t1 = bf2f((unsigned short)v2[j]) + bf2f((unsigned short)v3[j]);
                    acc[j] += t0 + t1;
                }
            }
            for (; e < eend; ++e) {
                short8 v0 = hb8[es[e] * 16 + c8];
#pragma unroll
                for (int j = 0; j < 8; ++j) acc[j] += bf2f((unsigned short)v0[j]);
            }
        } else {
            for (; e + 1 < eend; e += 2) {
                int s0 = es[e], s1 = es[e + 1];
                float4 u0 = h4[s0 * 32 + c8 * 2], u1 = h4[s0 * 32 + c8 * 2 + 1];
                float4 w0 = h4[s1 * 32 + c8 * 2], w1 = h4[s1 * 32 + c8 * 2 + 1];
                acc[0] += u0.x + w0.x; acc[1] += u0.y + w0.y;
                acc[2] += u0.z + w0.z; acc[3] += u0.w + w0.w;
                acc[4] += u1.x + w1.x; acc[5] += u1.y + w1.y;
                acc[6] += u1.z + w1.z; acc[7] += u1.w + w1.w;
            }
            if (e < eend) {
                int s0 = es[e];
                float4 u0 = h4[s0 * 32 + c8 * 2], u1 = h4[s0 * 32 + c8 * 2 + 1];
                acc[0] += u0.x; acc[1] += u0.y; acc[2] += u0.z; acc[3] += u0.w;
                acc[4] += u1.x; acc[5] += u1.y; acc[6] += u1.z; acc[7] += u1.w;
            }
        }
        short8 o;
#pragma unroll
        for (int j = 0; j < 8; ++j) o[j] = (short)f2bf(acc[j]);
        ((short8*)xb)[node * 16 + c8] = o;
    }
}

// ---------------------------------------------------------------------------
// Kernel 3: fused MLP: Y = relu(X@W1+b1)@W2 + b2, bf16 MFMA, Y1 stays in
// LDS; epilogue accumulates BN column sums/sumsq (valid rows only).
// ---------------------------------------------------------------------------
__global__ __launch_bounds__(256) void mlp_fused_kernel(
    const unsigned short* __restrict__ X,
    const unsigned short* __restrict__ W1t, const unsigned short* __restrict__ W2t,
    const float* __restrict__ b1, const float* __restrict__ b2,
    unsigned short* __restrict__ Y, float* __restrict__ stats)
{
    extern __shared__ char smem[];
    unsigned short* wl = (unsigned short*)smem;            // [128][136] bf16
    unsigned short* xl = (unsigned short*)(smem + 34816);  // [64][136] bf16

    const int tid = threadIdx.x;
    const int r0 = blockIdx.x * 64;
    const int lane = tid & 63;
    const int wv = tid >> 6;
    const int m = lane & 15;
    const int hi = lane >> 4;

    const short8* W18 = (const short8*)W1t;
#pragma unroll
    for (int l = 0; l < 8; ++l) {
        int idx = tid + l * 256;
        int n = idx >> 4, c = idx & 15;
        *(short8*)&wl[n * 136 + c * 8] = W18[idx];
    }
    const short8* X8 = (const short8*)X;
#pragma unroll
    for (int l = 0; l < 4; ++l) {
        int idx = tid + l * 256;
        int row = idx >> 4, c = idx & 15;
        int g = r0 + row;
        short8 v = {0, 0, 0, 0, 0, 0, 0, 0};
        if (g < NN) v = X8[g * 16 + c];
        *(short8*)&xl[row * 136 + c * 8] = v;
    }
    __syncthreads();

    floatx4 acc[8];
#pragma unroll
    for (int i = 0; i < 8; ++i) acc[i] = (floatx4){0.f, 0.f, 0.f, 0.f};
#pragma unroll
    for (int kc = 0; kc < 4; ++kc) {
        short8 a = *(const short8*)&xl[(wv * 16 + m) * 136 + kc * 32 + hi * 8];
#pragma unroll
        for (int nt = 0; nt < 8; ++nt) {
            short8 b = *(const short8*)&wl[(nt * 16 + m) * 136 + kc * 32 + hi * 8];
            acc[nt] = __builtin_amdgcn_mfma_f32_16x16x32_bf16(a, b, acc[nt], 0, 0, 0);
        }
    }
    __syncthreads();

#pragma unroll
    for (int nt = 0; nt < 8; ++nt) {
        float bv = b1[nt * 16 + m];
#pragma unroll
        for (int r = 0; r < 4; ++r) {
            float v = fmaxf(acc[nt][r] + bv, 0.f);
            xl[(wv * 16 + hi * 4 + r) * 136 + nt * 16 + m] = f2bf(v);
        }
    }
    const short8* W28 = (const short8*)W2t;
#pragma unroll
    for (int l = 0; l < 8; ++l) {
        int idx = tid + l * 256;
        int n = idx >> 4, c = idx & 15;
        *(short8*)&wl[n * 136 + c * 8] = W28[idx];
    }
    __syncthreads();

#pragma unroll
    for (int i = 0; i < 8; ++i) acc[i] = (floatx4){0.f, 0.f, 0.f, 0.f};
#pragma unroll
    for (int kc = 0; kc < 4; ++kc) {
        short8 a = *(const short8*)&xl[(wv * 16 + m) * 136 + kc * 32 + hi * 8];
#pragma unroll
        for (int nt = 0; nt < 8; ++nt) {
            short8 b = *(const short8*)&wl[(nt * 16 + m) * 136 + kc * 32 + hi * 8];
            acc[nt] = __builtin_amdgcn_mfma_f32_16x16x32_bf16(a, b, acc[nt], 0, 0, 0);
        }
    }
    __syncthreads();

#pragma unroll
    for (int nt = 0; nt < 8; ++nt) {
        float bv = b2[nt * 16 + m];
#pragma unroll
        for (int r = 0; r < 4; ++r) {
            float v = acc[nt][r] + bv;
            xl[(wv * 16 + hi * 4 + r) * 136 + nt * 16 + m] = f2bf(v);
        }
    }
    __syncthreads();

#pragma unroll
    for (int l = 0; l < 4; ++l) {
        int idx = tid + l * 256;
        int row = idx >> 4, c = idx & 15;
        int g = r0 + row;
        if (g < NN)
            ((short8*)Y)[g * 16 + c] = *(const short8*)&xl[row * 136 + c * 8];
    }

    int col = tid & 127, half = tid >> 7;
    int rlim = min(64, NN - r0);
    int rbeg = half * 32, rend = min(rbeg + 32, rlim);
    float s = 0.f, q = 0.f;
    for (int r = rbeg; r < rend; ++r) {
        float v = bf2f(xl[r * 136 + col]);
        s += v; q += v * v;
    }
    float* red = (float*)wl;
    red[tid] = s;
    red[256 + tid] = q;
    __syncthreads();
    if (half == 0) {
        atomicAdd(&stats[col],      red[col] + red[128 + col]);
        atomicAdd(&stats[DD + col], red[256 + col] + red[256 + 128 + col]);
    }
}

// ---------------------------------------------------------------------------
// Kernel 4: out = h + relu(Y*scale + shift). Grid stride is a multiple of
// 16, so each thread's column octet is fixed -> all BN math hoisted out of
// the streaming loop; Y read as short8 (16B/lane).
// ---------------------------------------------------------------------------
__global__ __launch_bounds__(256) void bn_final_kernel(
    const unsigned short* __restrict__ Y, const float* __restrict__ h,
    const float* __restrict__ gamma, const float* __restrict__ beta,
    const float* __restrict__ stats, float* __restrict__ out)
{
    const float invN = 1.0f / (float)NN;
    int t0 = blockIdx.x * 256 + threadIdx.x;
    int c8 = t0 & 15;
    float sc[8], sh[8];
#pragma unroll
    for (int j = 0; j < 8; ++j) {
        int col = c8 * 8 + j;
        float mu = stats[col] * invN;
        float var = stats[DD + col] * invN - mu * mu;
        float s = rsqrtf(var + BN_EPS) * gamma[col];
        sc[j] = s;
        sh[j] = beta[col] - mu * s;
    }
    const short8* Y8 = (const short8*)Y;
    const float4* H4 = (const float4*)h;
    float4* O4 = (float4*)out;
    const int total = NN * 16;
    const int stride = BN_BLOCKS * 256;
    for (int i = t0; i < total; i += stride) {
        short8 u = Y8[i];
        float4 h0 = H4[2 * i], h1 = H4[2 * i + 1];
        float4 r0, r1;
        r0.x = h0.x + fmaxf(bf2f((unsigned short)u[0]) * sc[0] + sh[0], 0.f);
        r0.y = h0.y + fmaxf(bf2f((unsigned short)u[1]) * sc[1] + sh[1], 0.f);
        r0.z = h0.z + fmaxf(bf2f((unsigned short)u[2]) * sc[2] + sh[2], 0.f);
        r0.w = h0.w + fmaxf(bf2f((unsigned short)u[3]) * sc[3] + sh[3], 0.f);
        r1.x = h1.x + fmaxf(bf2f((unsigned short)u[4]) * sc[4] + sh[4], 0.f);
        r1.y = h1.y + fmaxf(bf2f((unsigned short)u[5]) * sc[5] + sh[5], 0.f);
        r1.z = h1.z + fmaxf(bf2f((unsigned short)u[6]) * sc[6] + sh[6], 0.f);
        r1.w = h1.w + fmaxf(bf2f((unsigned short)u[7]) * sc[7] + sh[7], 0.f);
        O4[2 * i] = r0;
        O4[2 * i + 1] = r1;
    }
}

// ---------------------------------------------------------------------------
extern "C" void kernel_launch(void* const* d_in, const int* in_sizes, int n_in,
                              void* d_out, int out_size, void* d_ws, size_t ws_size,
                              hipStream_t stream)
{
    const float* h     = (const float*)d_in[0];
    const int*   src   = (const int*)d_in[1];
    const int*   dst   = (const int*)d_in[2];
    const float* eps   = (const float*)d_in[3];
    const float* W1    = (const float*)d_in[4];
    const float* b1    = (const float*)d_in[5];
    const float* W2    = (const float*)d_in[6];
    const float* b2    = (const float*)d_in[7];
    const float* gamma = (const float*)d_in[8];
    const float* beta  = (const float*)d_in[9];
    float* out = (float*)d_out;

    char* w = (char*)d_ws;
    size_t o = 0;
    float* stats    = (float*)(w + o); o += 256 * 4;
    int* wcnt       = (int*)(w + o); o += 1024 * 4;                  // NWIN used
    unsigned short* W1t = (unsigned short*)(w + o); o += (size_t)DD * DD * 2;
    unsigned short* W2t = (unsigned short*)(w + o); o += (size_t)DD * DD * 2;
    int* estage     = (int*)(w + o); o += (size_t)NWIN * CAP * 4;    // 9.6 MB
    unsigned short* xb  = (unsigned short*)(w + o); o += (size_t)NN * DD * 2;
    unsigned short* hb  = (unsigned short*)(w + o); o += (size_t)NN * DD * 2;
    const int use_hb = (ws_size >= o) ? 1 : 0;  // launch-constant

    // 0. zero window cursors (graph-capturable async memset)
    hipMemsetAsync(wcnt, 0, 1024 * sizeof(int), stream);

    // 1. fused prep + window scatter
    prep_scatter_kernel<<<GRID_PS, 256, 0, stream>>>(
        stats, W1, W2, W1t, W2t, h, hb, use_hb, src, dst, wcnt, estage);

    // 2. fused in-LDS permute + gather: xb = bf16((1+eps)*h + neighbor-sum)
    if (use_hb)
        permgather_kernel<true><<<NWIN, 512, 0, stream>>>(h, hb, eps, wcnt, estage, xb);
    else
        permgather_kernel<false><<<NWIN, 512, 0, stream>>>(h, hb, eps, wcnt, estage, xb);

    // 3. fused 2-layer MLP + BN stats
    int gemm_blocks = (NN + 63) / 64;  // 1563
    size_t gemm_lds = 34816 + 17408;   // 52224 B
    mlp_fused_kernel<<<gemm_blocks, 256, gemm_lds, stream>>>(xb, W1t, W2t, b1, b2, xb, stats);

    // 4. out = h + relu(BN(y2))
    bn_final_kernel<<<BN_BLOCKS, 256, 0, stream>>>(xb, h, gamma, beta, stats, out);
}

// Round 3
// 296.591 us; speedup vs baseline: 1.3661x; 1.0055x over previous
//
#include <hip/hip_runtime.h>

#define NN 100000
#define NE 1600000
#define DD 128
#define BN_EPS 1e-5f

#define NWIN 782                       // ceil(NN/128) 128-node windows
#define NWINP 1024                     // padded window count (scan-friendly)
#define EPB 8192                       // edges per scatter block
#define NBLK ((NE + EPB - 1) / EPB)    // 196 scatter blocks
#define CAP 3072                       // per-window slot capacity (mean 2046, max ~2250)
#define PREPBLKS 828                   // prep role blocks in fused kernel
#define GRID_PS (NBLK + PREPBLKS)      // 1024
#define BN_BLOCKS 1024

typedef __attribute__((ext_vector_type(8))) short short8;
typedef __attribute__((ext_vector_type(4))) float floatx4;

__device__ __forceinline__ unsigned short f2bf(float f) {
    union { float f; unsigned u; } v; v.f = f;
    return (unsigned short)((v.u + 0x7FFFu + ((v.u >> 16) & 1u)) >> 16);
}
__device__ __forceinline__ float bf2f(unsigned short u) {
    union { unsigned u; float f; } v; v.u = ((unsigned)u) << 16;
    return v.f;
}

// ---------------------------------------------------------------------------
// Kernel 1 (fused): blocks [0,196) = window scatter; blocks [196,1024) = prep.
// Scatter now does a block-local LDS bucket sort and copies CONTIGUOUS
// per-window runs to estage: each thread streams a sequential run, so 4B
// stores coalesce in L2 (vs the old random-slot writes that touched a
// distinct 64B line per edge: ~100MB -> ~15MB effective write traffic).
// wcnt must be zeroed by the preceding hipMemsetAsync.
// ---------------------------------------------------------------------------
__global__ __launch_bounds__(256) void prep_scatter_kernel(
    float* __restrict__ stats,
    const float* __restrict__ W1, const float* __restrict__ W2,
    unsigned short* __restrict__ W1t, unsigned short* __restrict__ W2t,
    const float* __restrict__ h, unsigned short* __restrict__ hb, int do_hb,
    const int* __restrict__ src, const int* __restrict__ dst,
    int* __restrict__ wcnt, int* __restrict__ estage)
{
    __shared__ int lofs[NWINP];   // local exclusive offsets (run begin)
    __shared__ int lcur[NWINP];   // counts -> cursor -> run end
    __shared__ int gbase[NWINP];  // reserved global base per window
    __shared__ int sorted[EPB];   // block-locally bucket-sorted entries
    __shared__ int stmp[256];     // block scan temp
    int t = threadIdx.x;

    if (blockIdx.x < NBLK) {
        // ---- scatter role ----
        int blk = blockIdx.x;
        for (int w = t; w < NWINP; w += 256) lcur[w] = 0;
        __syncthreads();
        int base = blk * EPB;
        int cnt = min(EPB, NE - base);
        for (int i = t; i < cnt; i += 256)
            atomicAdd(&lcur[dst[base + i] >> 7], 1);
        __syncthreads();

        // scan 1024 bins with 256 threads (4 consecutive bins per thread)
        int w0 = t * 4;
        int c0 = lcur[w0], c1 = lcur[w0 + 1], c2 = lcur[w0 + 2], c3 = lcur[w0 + 3];
        int tsum = c0 + c1 + c2 + c3;
        stmp[t] = tsum;
        __syncthreads();
#pragma unroll
        for (int ofs = 1; ofs < 256; ofs <<= 1) {
            int u = (t >= ofs) ? stmp[t - ofs] : 0;
            __syncthreads();
            stmp[t] += u;
            __syncthreads();
        }
        int excl = stmp[t] - tsum;
        lofs[w0]     = excl;
        lofs[w0 + 1] = excl + c0;
        lofs[w0 + 2] = excl + c0 + c1;
        lofs[w0 + 3] = excl + c0 + c1 + c2;
        // reserve global chunks (one atomic per nonzero window)
        int gb0 = (w0     < NWIN && c0) ? atomicAdd(&wcnt[w0],     c0) : 0;
        int gb1 = (w0 + 1 < NWIN && c1) ? atomicAdd(&wcnt[w0 + 1], c1) : 0;
        int gb2 = (w0 + 2 < NWIN && c2) ? atomicAdd(&wcnt[w0 + 2], c2) : 0;
        int gb3 = (w0 + 3 < NWIN && c3) ? atomicAdd(&wcnt[w0 + 3], c3) : 0;
        gbase[w0]     = w0 * CAP + gb0;
        gbase[w0 + 1] = (w0 + 1) * CAP + gb1;
        gbase[w0 + 2] = (w0 + 2) * CAP + gb2;
        gbase[w0 + 3] = (w0 + 3) * CAP + gb3;
        // counts consumed; turn lcur into local cursors
        lcur[w0] = lofs[w0]; lcur[w0 + 1] = lofs[w0 + 1];
        lcur[w0 + 2] = lofs[w0 + 2]; lcur[w0 + 3] = lofs[w0 + 3];
        __syncthreads();

        // pass A: LDS bucket sort (re-read src/dst: L1/L2-hot)
        for (int i = t; i < cnt; i += 256) {
            int d = dst[base + i];
            int s = src[base + i];
            int p = atomicAdd(&lcur[d >> 7], 1);
            sorted[p] = (s << 7) | (d & 127);
        }
        __syncthreads();

        // pass B: copy contiguous runs to global (lcur[w] is now run end)
        for (int w = t; w < NWIN; w += 256) {
            int lb = lofs[w], le = lcur[w];
            int g = gbase[w];
            for (int j = lb; j < le; ++j)
                estage[g + (j - lb)] = sorted[j];
        }
    } else {
        // ---- prep role ----
        int tid0 = (blockIdx.x - NBLK) * 256 + t;
        int stride = PREPBLKS * 256;
        if (tid0 < 2 * DD) stats[tid0] = 0.0f;
        for (int i = tid0; i < DD * DD; i += stride) {
            int n = i >> 7, k = i & 127;
            W1t[i] = f2bf(W1[k * DD + n]);
            W2t[i] = f2bf(W2[k * DD + n]);
        }
        if (do_hb) {
            const float4* h4 = (const float4*)h;
            ushort4* hb4 = (ushort4*)hb;
            for (int i = tid0; i < NN * (DD / 4); i += stride) {
                float4 v = h4[i];
                ushort4 o;
                o.x = f2bf(v.x); o.y = f2bf(v.y); o.z = f2bf(v.z); o.w = f2bf(v.w);
                hb4[i] = o;
            }
        }
    }
}

// ---------------------------------------------------------------------------
// Kernel 2 (fused): per-window CSR permute in LDS + degree-sorted gather.
// 256-thread blocks (8 resident/CU target: LDS ~16.5KB) so permute phases of
// some blocks overlap gather phases of others. Nodes are counting-sorted by
// degree so each 16-lane x 4-node wave group has uniform trip counts
// (removes ~27% lane idle from E[max of 4 Poisson(16)] divergence).
// ---------------------------------------------------------------------------
template <bool HB>
__global__ __launch_bounds__(256) void permgather_kernel(
    const float* __restrict__ h, const unsigned short* __restrict__ hb,
    const float* __restrict__ eps, const int* __restrict__ wcnt,
    const int* __restrict__ estage, unsigned short* __restrict__ xb)
{
    __shared__ int es[CAP];       // permuted src indices, CSR by node
    __shared__ int cnt[128];
    __shared__ int beg[128];
    __shared__ int cur[128];
    __shared__ int dh[64];        // degree histogram (capped 63)
    __shared__ int dcur[64];
    __shared__ unsigned char order[128];

    int b = blockIdx.x, t = threadIdx.x;
    if (t < 128) cnt[t] = 0;
    if (t < 64) dh[t] = 0;
    __syncthreads();

    int n = min(wcnt[b], CAP);
    int wbase = b * CAP;
    for (int i = t; i < n; i += 256)
        atomicAdd(&cnt[estage[wbase + i] & 127], 1);
    __syncthreads();

    // scan cnt -> beg (exclusive), build degree histogram
    if (t < 128) beg[t] = cnt[t];
    __syncthreads();
#pragma unroll
    for (int ofs = 1; ofs < 128; ofs <<= 1) {
        int u = (t < 128 && t >= ofs) ? beg[t - ofs] : 0;
        __syncthreads();
        if (t < 128) beg[t] += u;
        __syncthreads();
    }
    if (t < 128) {
        int ex = beg[t] - cnt[t];
        beg[t] = ex;
        cur[t] = ex;
        atomicAdd(&dh[min(cnt[t], 63)], 1);
    }
    __syncthreads();

    // scan degree histogram (64) -> exclusive, then scatter node ids
    if (t < 64) dcur[t] = dh[t];
    __syncthreads();
#pragma unroll
    for (int ofs = 1; ofs < 64; ofs <<= 1) {
        int u = (t < 64 && t >= ofs) ? dcur[t - ofs] : 0;
        __syncthreads();
        if (t < 64) dcur[t] += u;
        __syncthreads();
    }
    if (t < 64) dcur[t] -= dh[t];
    __syncthreads();
    if (t < 128) {
        int p = atomicAdd(&dcur[min(cnt[t], 63)], 1);
        order[p] = (unsigned char)t;
    }
    __syncthreads();

    // permute pass (re-read estage: L2-resident)
    for (int i = t; i < n; i += 256) {
        int e = estage[wbase + i];
        int p = atomicAdd(&cur[e & 127], 1);
        es[p] = e >> 7;
    }
    __syncthreads();

    // ---- gather: 16 nodes per pass (16 lanes/node), degree-sorted order ----
    const float sE = 1.0f + eps[0];
    const float4* h4 = (const float4*)h;
    const short8* hb8 = (const short8*)hb;
    int c8 = t & 15;
#pragma unroll
    for (int pass = 0; pass < 8; ++pass) {
        int nl = order[pass * 16 + (t >> 4)];
        int node = (b << 7) + nl;
        if (node >= NN) continue;
        float4 a0 = h4[node * 32 + c8 * 2];
        float4 a1 = h4[node * 32 + c8 * 2 + 1];
        float acc[8] = {sE * a0.x, sE * a0.y, sE * a0.z, sE * a0.w,
                        sE * a1.x, sE * a1.y, sE * a1.z, sE * a1.w};
        int e = beg[nl], eend = beg[nl] + cnt[nl];
        if (HB) {
            for (; e + 3 < eend; e += 4) {
                int s0 = es[e], s1 = es[e + 1], s2 = es[e + 2], s3 = es[e + 3];
                short8 v0 = hb8[s0 * 16 + c8];
                short8 v1 = hb8[s1 * 16 + c8];
                short8 v2 = hb8[s2 * 16 + c8];
                short8 v3 = hb8[s3 * 16 + c8];
#pragma unroll
                for (int j = 0; j < 8; ++j) {
                    float t0 = bf2f((unsigned short)v0[j]) + bf2f((unsigned short)v1[j]);
                    float t1 = bf2f((unsigned short)v2[j]) + bf2f((unsigned short)v3[j]);
                    acc[j] += t0 + t1;
                }
            }
            for (; e < eend; ++e) {
                short8 v0 = hb8[es[e] * 16 + c8];
#pragma unroll
                for (int j = 0; j < 8; ++j) acc[j] += bf2f((unsigned short)v0[j]);
            }
        } else {
            for (; e + 1 < eend; e += 2) {
                int s0 = es[e], s1 = es[e + 1];
                float4 u0 = h4[s0 * 32 + c8 * 2], u1 = h4[s0 * 32 + c8 * 2 + 1];
                float4 w0 = h4[s1 * 32 + c8 * 2], w1 = h4[s1 * 32 + c8 * 2 + 1];
                acc[0] += u0.x + w0.x; acc[1] += u0.y + w0.y;
                acc[2] += u0.z + w0.z; acc[3] += u0.w + w0.w;
                acc[4] += u1.x + w1.x; acc[5] += u1.y + w1.y;
                acc[6] += u1.z + w1.z; acc[7] += u1.w + w1.w;
            }
            if (e < eend) {
                int s0 = es[e];
                float4 u0 = h4[s0 * 32 + c8 * 2], u1 = h4[s0 * 32 + c8 * 2 + 1];
                acc[0] += u0.x; acc[1] += u0.y; acc[2] += u0.z; acc[3] += u0.w;
                acc[4] += u1.x; acc[5] += u1.y; acc[6] += u1.z; acc[7] += u1.w;
            }
        }
        short8 o;
#pragma unroll
        for (int j = 0; j < 8; ++j) o[j] = (short)f2bf(acc[j]);
        ((short8*)xb)[node * 16 + c8] = o;
    }
}

// ---------------------------------------------------------------------------
// Kernel 3: fused MLP: Y = relu(X@W1+b1)@W2 + b2, bf16 MFMA, Y1 stays in
// LDS; epilogue accumulates BN column sums/sumsq (valid rows only).
// ---------------------------------------------------------------------------
__global__ __launch_bounds__(256) void mlp_fused_kernel(
    const unsigned short* __restrict__ X,
    const unsigned short* __restrict__ W1t, const unsigned short* __restrict__ W2t,
    const float* __restrict__ b1, const float* __restrict__ b2,
    unsigned short* __restrict__ Y, float* __restrict__ stats)
{
    extern __shared__ char smem[];
    unsigned short* wl = (unsigned short*)smem;            // [128][136] bf16
    unsigned short* xl = (unsigned short*)(smem + 34816);  // [64][136] bf16

    const int tid = threadIdx.x;
    const int r0 = blockIdx.x * 64;
    const int lane = tid & 63;
    const int wv = tid >> 6;
    const int m = lane & 15;
    const int hi = lane >> 4;

    const short8* W18 = (const short8*)W1t;
#pragma unroll
    for (int l = 0; l < 8; ++l) {
        int idx = tid + l * 256;
        int n = idx >> 4, c = idx & 15;
        *(short8*)&wl[n * 136 + c * 8] = W18[idx];
    }
    const short8* X8 = (const short8*)X;
#pragma unroll
    for (int l = 0; l < 4; ++l) {
        int idx = tid + l * 256;
        int row = idx >> 4, c = idx & 15;
        int g = r0 + row;
        short8 v = {0, 0, 0, 0, 0, 0, 0, 0};
        if (g < NN) v = X8[g * 16 + c];
        *(short8*)&xl[row * 136 + c * 8] = v;
    }
    __syncthreads();

    floatx4 acc[8];
#pragma unroll
    for (int i = 0; i < 8; ++i) acc[i] = (floatx4){0.f, 0.f, 0.f, 0.f};
#pragma unroll
    for (int kc = 0; kc < 4; ++kc) {
        short8 a = *(const short8*)&xl[(wv * 16 + m) * 136 + kc * 32 + hi * 8];
#pragma unroll
        for (int nt = 0; nt < 8; ++nt) {
            short8 b = *(const short8*)&wl[(nt * 16 + m) * 136 + kc * 32 + hi * 8];
            acc[nt] = __builtin_amdgcn_mfma_f32_16x16x32_bf16(a, b, acc[nt], 0, 0, 0);
        }
    }
    __syncthreads();

#pragma unroll
    for (int nt = 0; nt < 8; ++nt) {
        float bv = b1[nt * 16 + m];
#pragma unroll
        for (int r = 0; r < 4; ++r) {
            float v = fmaxf(acc[nt][r] + bv, 0.f);
            xl[(wv * 16 + hi * 4 + r) * 136 + nt * 16 + m] = f2bf(v);
        }
    }
    const short8* W28 = (const short8*)W2t;
#pragma unroll
    for (int l = 0; l < 8; ++l) {
        int idx = tid + l * 256;
        int n = idx >> 4, c = idx & 15;
        *(short8*)&wl[n * 136 + c * 8] = W28[idx];
    }
    __syncthreads();

#pragma unroll
    for (int i = 0; i < 8; ++i) acc[i] = (floatx4){0.f, 0.f, 0.f, 0.f};
#pragma unroll
    for (int kc = 0; kc < 4; ++kc) {
        short8 a = *(const short8*)&xl[(wv * 16 + m) * 136 + kc * 32 + hi * 8];
#pragma unroll
        for (int nt = 0; nt < 8; ++nt) {
            short8 b = *(const short8*)&wl[(nt * 16 + m) * 136 + kc * 32 + hi * 8];
            acc[nt] = __builtin_amdgcn_mfma_f32_16x16x32_bf16(a, b, acc[nt], 0, 0, 0);
        }
    }
    __syncthreads();

#pragma unroll
    for (int nt = 0; nt < 8; ++nt) {
        float bv = b2[nt * 16 + m];
#pragma unroll
        for (int r = 0; r < 4; ++r) {
            float v = acc[nt][r] + bv;
            xl[(wv * 16 + hi * 4 + r) * 136 + nt * 16 + m] = f2bf(v);
        }
    }
    __syncthreads();

#pragma unroll
    for (int l = 0; l < 4; ++l) {
        int idx = tid + l * 256;
        int row = idx >> 4, c = idx & 15;
        int g = r0 + row;
        if (g < NN)
            ((short8*)Y)[g * 16 + c] = *(const short8*)&xl[row * 136 + c * 8];
    }

    int col = tid & 127, half = tid >> 7;
    int rlim = min(64, NN - r0);
    int rbeg = half * 32, rend = min(rbeg + 32, rlim);
    float s = 0.f, q = 0.f;
    for (int r = rbeg; r < rend; ++r) {
        float v = bf2f(xl[r * 136 + col]);
        s += v; q += v * v;
    }
    float* red = (float*)wl;
    red[tid] = s;
    red[256 + tid] = q;
    __syncthreads();
    if (half == 0) {
        atomicAdd(&stats[col],      red[col] + red[128 + col]);
        atomicAdd(&stats[DD + col], red[256 + col] + red[256 + 128 + col]);
    }
}

// ---------------------------------------------------------------------------
// Kernel 4: out = h + relu(Y*scale + shift). Thread's column octet is fixed
// across the grid-stride loop -> BN math hoisted; Y read as short8.
// ---------------------------------------------------------------------------
__global__ __launch_bounds__(256) void bn_final_kernel(
    const unsigned short* __restrict__ Y, const float* __restrict__ h,
    const float* __restrict__ gamma, const float* __restrict__ beta,
    const float* __restrict__ stats, float* __restrict__ out)
{
    const float invN = 1.0f / (float)NN;
    int t0 = blockIdx.x * 256 + threadIdx.x;
    int c8 = t0 & 15;
    float sc[8], sh[8];
#pragma unroll
    for (int j = 0; j < 8; ++j) {
        int col = c8 * 8 + j;
        float mu = stats[col] * invN;
        float var = stats[DD + col] * invN - mu * mu;
        float s = rsqrtf(var + BN_EPS) * gamma[col];
        sc[j] = s;
        sh[j] = beta[col] - mu * s;
    }
    const short8* Y8 = (const short8*)Y;
    const float4* H4 = (const float4*)h;
    float4* O4 = (float4*)out;
    const int total = NN * 16;
    const int stride = BN_BLOCKS * 256;
    for (int i = t0; i < total; i += stride) {
        short8 u = Y8[i];
        float4 h0 = H4[2 * i], h1 = H4[2 * i + 1];
        float4 r0, r1;
        r0.x = h0.x + fmaxf(bf2f((unsigned short)u[0]) * sc[0] + sh[0], 0.f);
        r0.y = h0.y + fmaxf(bf2f((unsigned short)u[1]) * sc[1] + sh[1], 0.f);
        r0.z = h0.z + fmaxf(bf2f((unsigned short)u[2]) * sc[2] + sh[2], 0.f);
        r0.w = h0.w + fmaxf(bf2f((unsigned short)u[3]) * sc[3] + sh[3], 0.f);
        r1.x = h1.x + fmaxf(bf2f((unsigned short)u[4]) * sc[4] + sh[4], 0.f);
        r1.y = h1.y + fmaxf(bf2f((unsigned short)u[5]) * sc[5] + sh[5], 0.f);
        r1.z = h1.z + fmaxf(bf2f((unsigned short)u[6]) * sc[6] + sh[6], 0.f);
        r1.w = h1.w + fmaxf(bf2f((unsigned short)u[7]) * sc[7] + sh[7], 0.f);
        O4[2 * i] = r0;
        O4[2 * i + 1] = r1;
    }
}

// ---------------------------------------------------------------------------
extern "C" void kernel_launch(void* const* d_in, const int* in_sizes, int n_in,
                              void* d_out, int out_size, void* d_ws, size_t ws_size,
                              hipStream_t stream)
{
    const float* h     = (const float*)d_in[0];
    const int*   src   = (const int*)d_in[1];
    const int*   dst   = (const int*)d_in[2];
    const float* eps   = (const float*)d_in[3];
    const float* W1    = (const float*)d_in[4];
    const float* b1    = (const float*)d_in[5];
    const float* W2    = (const float*)d_in[6];
    const float* b2    = (const float*)d_in[7];
    const float* gamma = (const float*)d_in[8];
    const float* beta  = (const float*)d_in[9];
    float* out = (float*)d_out;

    char* w = (char*)d_ws;
    size_t o = 0;
    float* stats    = (float*)(w + o); o += 256 * 4;
    int* wcnt       = (int*)(w + o); o += 1024 * 4;                  // NWIN used
    unsigned short* W1t = (unsigned short*)(w + o); o += (size_t)DD * DD * 2;
    unsigned short* W2t = (unsigned short*)(w + o); o += (size_t)DD * DD * 2;
    int* estage     = (int*)(w + o); o += (size_t)NWIN * CAP * 4;    // 9.6 MB
    unsigned short* xb  = (unsigned short*)(w + o); o += (size_t)NN * DD * 2;
    unsigned short* hb  = (unsigned short*)(w + o); o += (size_t)NN * DD * 2;
    const int use_hb = (ws_size >= o) ? 1 : 0;  // launch-constant

    // 0. zero window cursors (graph-capturable async memset)
    hipMemsetAsync(wcnt, 0, 1024 * sizeof(int), stream);

    // 1. fused prep + write-combined window scatter
    prep_scatter_kernel<<<GRID_PS, 256, 0, stream>>>(
        stats, W1, W2, W1t, W2t, h, hb, use_hb, src, dst, wcnt, estage);

    // 2. fused in-LDS permute + degree-sorted gather
    if (use_hb)
        permgather_kernel<true><<<NWIN, 256, 0, stream>>>(h, hb, eps, wcnt, estage, xb);
    else
        permgather_kernel<false><<<NWIN, 256, 0, stream>>>(h, hb, eps, wcnt, estage, xb);

    // 3. fused 2-layer MLP + BN stats
    int gemm_blocks = (NN + 63) / 64;  // 1563
    size_t gemm_lds = 34816 + 17408;   // 52224 B
    mlp_fused_kernel<<<gemm_blocks, 256, gemm_lds, stream>>>(xb, W1t, W2t, b1, b2, xb, stats);

    // 4. out = h + relu(BN(y2))
    bn_final_kernel<<<BN_BLOCKS, 256, 0, stream>>>(xb, h, gamma, beta, stats, out);
}

// Round 4
// 287.058 us; speedup vs baseline: 1.4114x; 1.0332x over previous
//
#include <hip/hip_runtime.h>

#define NN 100000
#define NE 1600000
#define DD 128
#define BN_EPS 1e-5f

#define WSH 6                          // log2(window size)
#define WSZ 64                         // nodes per window
#define NWIN ((NN + WSZ - 1) / WSZ)    // 1563 windows
#define NWINP 2048                     // padded for the block scan
#define EPB 8192                       // edges per scatter block
#define NBLK ((NE + EPB - 1) / EPB)    // 196 scatter blocks
#define CAP 1536                       // per-window capacity (mean 1023, max ~1160)
#define PREPBLKS 828
#define GRID_PS (NBLK + PREPBLKS)      // 1024
#define BN_BLOCKS 1024

typedef __attribute__((ext_vector_type(8))) short short8;
typedef __attribute__((ext_vector_type(4))) float floatx4;

__device__ __forceinline__ unsigned short f2bf(float f) {
    union { float f; unsigned u; } v; v.f = f;
    return (unsigned short)((v.u + 0x7FFFu + ((v.u >> 16) & 1u)) >> 16);
}
__device__ __forceinline__ float bf2f(unsigned short u) {
    union { unsigned u; float f; } v; v.u = ((unsigned)u) << 16;
    return v.f;
}

// ---------------------------------------------------------------------------
// Kernel 1 (fused): blocks [0,196) = write-combined window scatter (block-
// local LDS bucket sort, contiguous per-window runs to estage); blocks
// [196,1024) = prep (zero stats, W->bf16 transpose, h->bf16 copy).
// wcnt must be zeroed by the preceding hipMemsetAsync.
// ---------------------------------------------------------------------------
__global__ __launch_bounds__(256) void prep_scatter_kernel(
    float* __restrict__ stats,
    const float* __restrict__ W1, const float* __restrict__ W2,
    unsigned short* __restrict__ W1t, unsigned short* __restrict__ W2t,
    const float* __restrict__ h, unsigned short* __restrict__ hb, int do_hb,
    const int* __restrict__ src, const int* __restrict__ dst,
    int* __restrict__ wcnt, int* __restrict__ estage)
{
    __shared__ int lofs[NWINP];   // run begin (local)
    __shared__ int lcur[NWINP];   // counts -> cursor -> run end
    __shared__ int gbase[NWINP];  // reserved global base per window
    __shared__ int sorted[EPB];   // block-locally bucket-sorted entries
    __shared__ int stmp[256];
    int t = threadIdx.x;

    if (blockIdx.x < NBLK) {
        int blk = blockIdx.x;
        for (int w = t; w < NWINP; w += 256) lcur[w] = 0;
        __syncthreads();
        int base = blk * EPB;
        int cnt = min(EPB, NE - base);
        for (int i = t; i < cnt; i += 256)
            atomicAdd(&lcur[dst[base + i] >> WSH], 1);
        __syncthreads();

        // scan 2048 bins: 8 consecutive bins per thread + block scan
        int w0 = t * 8;
        int c[8];
        int tsum = 0;
#pragma unroll
        for (int j = 0; j < 8; ++j) { c[j] = lcur[w0 + j]; tsum += c[j]; }
        stmp[t] = tsum;
        __syncthreads();
#pragma unroll
        for (int ofs = 1; ofs < 256; ofs <<= 1) {
            int u = (t >= ofs) ? stmp[t - ofs] : 0;
            __syncthreads();
            stmp[t] += u;
            __syncthreads();
        }
        int excl = stmp[t] - tsum;
#pragma unroll
        for (int j = 0; j < 8; ++j) {
            int w = w0 + j;
            lofs[w] = excl;
            lcur[w] = excl;   // cursor for pass A
            int gb = (w < NWIN && c[j]) ? atomicAdd(&wcnt[w], c[j]) : 0;
            gbase[w] = w * CAP + gb;
            excl += c[j];
        }
        __syncthreads();

        // pass A: LDS bucket sort (src/dst re-read is L2-hot)
        for (int i = t; i < cnt; i += 256) {
            int d = dst[base + i];
            int s = src[base + i];
            int p = atomicAdd(&lcur[d >> WSH], 1);
            sorted[p] = (s << WSH) | (d & (WSZ - 1));
        }
        __syncthreads();

        // pass B: copy contiguous runs to global (write-combining in L2)
        for (int w = t; w < NWIN; w += 256) {
            int lb = lofs[w], le = lcur[w];
            int g = gbase[w];
            for (int j = lb; j < le; ++j)
                estage[g + (j - lb)] = sorted[j];
        }
    } else {
        int tid0 = (blockIdx.x - NBLK) * 256 + t;
        int stride = PREPBLKS * 256;
        if (tid0 < 2 * DD) stats[tid0] = 0.0f;
        for (int i = tid0; i < DD * DD; i += stride) {
            int n = i >> 7, k = i & 127;
            W1t[i] = f2bf(W1[k * DD + n]);
            W2t[i] = f2bf(W2[k * DD + n]);
        }
        if (do_hb) {
            const float4* h4 = (const float4*)h;
            ushort4* hb4 = (ushort4*)hb;
            for (int i = tid0; i < NN * (DD / 4); i += stride) {
                float4 v = h4[i];
                ushort4 o;
                o.x = f2bf(v.x); o.y = f2bf(v.y); o.z = f2bf(v.z); o.w = f2bf(v.w);
                hb4[i] = o;
            }
        }
    }
}

// ---------------------------------------------------------------------------
// Kernel 2 (fused): per-window permute + degree-sorted gather + 2-layer MLP
// + BN-stat accumulation. 64-node windows, 256 threads (4 waves), 34.8 KB
// LDS -> 4 blocks/CU (16 waves). The gather tile x goes straight to LDS and
// is consumed by bf16 MFMA with half-staged weights (64 output cols at a
// time, in the union region that held the permute scratch). BN column
// sums/sumsq come from the f32 accumulators (masked to valid rows), one
// atomicAdd per column per block. Y2 (bf16) is the only global output.
// ---------------------------------------------------------------------------
template <bool HB>
__global__ __launch_bounds__(256) void permgather_mlp_kernel(
    const float* __restrict__ h, const unsigned short* __restrict__ hb,
    const float* __restrict__ eps, const int* __restrict__ wcnt,
    const int* __restrict__ estage,
    const unsigned short* __restrict__ W1t, const unsigned short* __restrict__ W2t,
    const float* __restrict__ b1, const float* __restrict__ b2,
    unsigned short* __restrict__ Y, float* __restrict__ stats)
{
    __shared__ __align__(16) unsigned short xl[WSZ * 136];  // 17408 B: x -> Y1 -> Y2
    __shared__ __align__(16) char un[17408];                // union region

    // permute-phase views of the union region
    int* es   = (int*)un;                       // [1536]
    int* cnt  = (int*)(un + 6144);              // [64]
    int* beg  = (int*)(un + 6144 + 256);        // [64]
    int* cur  = (int*)(un + 6144 + 512);        // [64]
    int* dh   = (int*)(un + 6144 + 768);        // [64]
    int* dcur = (int*)(un + 6144 + 1024);       // [64]
    unsigned char* order = (unsigned char*)(un + 6144 + 1280);  // [64]
    // MLP-phase views
    unsigned short* wl = (unsigned short*)un;   // [64][136] bf16 (W half)
    float* sred = (float*)un;                   // [128][16]
    float* qred = sred + 2048;                  // [128][16]

    const int b = blockIdx.x;
    const int t = threadIdx.x;
    const int lane = t & 63;
    const int wv = t >> 6;
    const int m = lane & 15;
    const int hi = lane >> 4;

    // ---- phase 1: per-node histogram + scan + degree sort + permute ----
    if (t < 64) { cnt[t] = 0; dh[t] = 0; }
    __syncthreads();
    int n = min(wcnt[b], CAP);
    int wbase = b * CAP;
    for (int i = t; i < n; i += 256)
        atomicAdd(&cnt[estage[wbase + i] & (WSZ - 1)], 1);
    __syncthreads();
    if (t < 64) beg[t] = cnt[t];
    __syncthreads();
#pragma unroll
    for (int ofs = 1; ofs < 64; ofs <<= 1) {
        int u = (t < 64 && t >= ofs) ? beg[t - ofs] : 0;
        __syncthreads();
        if (t < 64) beg[t] += u;
        __syncthreads();
    }
    if (t < 64) {
        int ex = beg[t] - cnt[t];
        beg[t] = ex;
        cur[t] = ex;
        atomicAdd(&dh[min(cnt[t], 63)], 1);
    }
    __syncthreads();
    if (t < 64) dcur[t] = dh[t];
    __syncthreads();
#pragma unroll
    for (int ofs = 1; ofs < 64; ofs <<= 1) {
        int u = (t < 64 && t >= ofs) ? dcur[t - ofs] : 0;
        __syncthreads();
        if (t < 64) dcur[t] += u;
        __syncthreads();
    }
    if (t < 64) dcur[t] -= dh[t];
    __syncthreads();
    if (t < 64) {
        int p = atomicAdd(&dcur[min(cnt[t], 63)], 1);
        order[p] = (unsigned char)t;
    }
    __syncthreads();
    for (int i = t; i < n; i += 256) {
        int e = estage[wbase + i];
        int p = atomicAdd(&cur[e & (WSZ - 1)], 1);
        es[p] = e >> WSH;
    }
    __syncthreads();

    // ---- phase 2: gather (16 lanes/node, 4 nodes/wave, degree-sorted) ----
    const float sE = 1.0f + eps[0];
    const float4* h4 = (const float4*)h;
    const short8* hb8 = (const short8*)hb;
    const int c8 = t & 15;
#pragma unroll
    for (int pass = 0; pass < 4; ++pass) {
        int nl = order[pass * 16 + (t >> 4)];
        int node = b * WSZ + nl;
        if (node >= NN) {
            short8 z = {0, 0, 0, 0, 0, 0, 0, 0};
            *(short8*)&xl[nl * 136 + c8 * 8] = z;  // keep MFMA input finite
            continue;
        }
        float4 a0 = h4[node * 32 + c8 * 2];
        float4 a1 = h4[node * 32 + c8 * 2 + 1];
        float acc[8] = {sE * a0.x, sE * a0.y, sE * a0.z, sE * a0.w,
                        sE * a1.x, sE * a1.y, sE * a1.z, sE * a1.w};
        int e = beg[nl], eend = beg[nl] + cnt[nl];
        if (HB) {
            for (; e + 3 < eend; e += 4) {
                int s0 = es[e], s1 = es[e + 1], s2 = es[e + 2], s3 = es[e + 3];
                short8 v0 = hb8[s0 * 16 + c8];
                short8 v1 = hb8[s1 * 16 + c8];
                short8 v2 = hb8[s2 * 16 + c8];
                short8 v3 = hb8[s3 * 16 + c8];
#pragma unroll
                for (int j = 0; j < 8; ++j) {
                    float t0 = bf2f((unsigned short)v0[j]) + bf2f((unsigned short)v1[j]);
                    float t1 = bf2f((unsigned short)v2[j]) + bf2f((unsigned short)v3[j]);
                    acc[j] += t0 + t1;
                }
            }
            for (; e < eend; ++e) {
                short8 v0 = hb8[es[e] * 16 + c8];
#pragma unroll
                for (int j = 0; j < 8; ++j) acc[j] += bf2f((unsigned short)v0[j]);
            }
        } else {
            for (; e + 1 < eend; e += 2) {
                int s0 = es[e], s1 = es[e + 1];
                float4 u0 = h4[s0 * 32 + c8 * 2], u1 = h4[s0 * 32 + c8 * 2 + 1];
                float4 w0 = h4[s1 * 32 + c8 * 2], w1 = h4[s1 * 32 + c8 * 2 + 1];
                acc[0] += u0.x + w0.x; acc[1] += u0.y + w0.y;
                acc[2] += u0.z + w0.z; acc[3] += u0.w + w0.w;
                acc[4] += u1.x + w1.x; acc[5] += u1.y + w1.y;
                acc[6] += u1.z + w1.z; acc[7] += u1.w + w1.w;
            }
            if (e < eend) {
                int s0 = es[e];
                float4 u0 = h4[s0 * 32 + c8 * 2], u1 = h4[s0 * 32 + c8 * 2 + 1];
                acc[0] += u0.x; acc[1] += u0.y; acc[2] += u0.z; acc[3] += u0.w;
                acc[4] += u1.x; acc[5] += u1.y; acc[6] += u1.z; acc[7] += u1.w;
            }
        }
        short8 o;
#pragma unroll
        for (int j = 0; j < 8; ++j) o[j] = (short)f2bf(acc[j]);
        *(short8*)&xl[nl * 136 + c8 * 8] = o;
    }
    __syncthreads();  // xl complete; es/scratch dead -> union becomes wl

    // ---- phase 3: GEMM1 (Y1 = relu(x@W1+b1)), W half-staged ----
    floatx4 acc[8];
#pragma unroll
    for (int i = 0; i < 8; ++i) acc[i] = (floatx4){0.f, 0.f, 0.f, 0.f};
    const short8* W1t8 = (const short8*)W1t;
#pragma unroll
    for (int hh = 0; hh < 2; ++hh) {
#pragma unroll
        for (int l = 0; l < 4; ++l) {
            int idx = t + l * 256;
            int nr = idx >> 4, c = idx & 15;
            *(short8*)&wl[nr * 136 + c * 8] = W1t8[(hh * 64 + nr) * 16 + c];
        }
        __syncthreads();
#pragma unroll
        for (int kc = 0; kc < 4; ++kc) {
            short8 a = *(const short8*)&xl[(wv * 16 + m) * 136 + kc * 32 + hi * 8];
#pragma unroll
            for (int ntl = 0; ntl < 4; ++ntl) {
                short8 bb = *(const short8*)&wl[(ntl * 16 + m) * 136 + kc * 32 + hi * 8];
                acc[hh * 4 + ntl] =
                    __builtin_amdgcn_mfma_f32_16x16x32_bf16(a, bb, acc[hh * 4 + ntl], 0, 0, 0);
            }
        }
        __syncthreads();
    }
    // write Y1 into xl
#pragma unroll
    for (int nt = 0; nt < 8; ++nt) {
        float bv = b1[nt * 16 + m];
#pragma unroll
        for (int r = 0; r < 4; ++r) {
            float v = fmaxf(acc[nt][r] + bv, 0.f);
            xl[(wv * 16 + hi * 4 + r) * 136 + nt * 16 + m] = f2bf(v);
        }
    }
    __syncthreads();

    // ---- phase 4: GEMM2 (Y2 = Y1@W2+b2) ----
#pragma unroll
    for (int i = 0; i < 8; ++i) acc[i] = (floatx4){0.f, 0.f, 0.f, 0.f};
    const short8* W2t8 = (const short8*)W2t;
#pragma unroll
    for (int hh = 0; hh < 2; ++hh) {
#pragma unroll
        for (int l = 0; l < 4; ++l) {
            int idx = t + l * 256;
            int nr = idx >> 4, c = idx & 15;
            *(short8*)&wl[nr * 136 + c * 8] = W2t8[(hh * 64 + nr) * 16 + c];
        }
        __syncthreads();
#pragma unroll
        for (int kc = 0; kc < 4; ++kc) {
            short8 a = *(const short8*)&xl[(wv * 16 + m) * 136 + kc * 32 + hi * 8];
#pragma unroll
            for (int ntl = 0; ntl < 4; ++ntl) {
                short8 bb = *(const short8*)&wl[(ntl * 16 + m) * 136 + kc * 32 + hi * 8];
                acc[hh * 4 + ntl] =
                    __builtin_amdgcn_mfma_f32_16x16x32_bf16(a, bb, acc[hh * 4 + ntl], 0, 0, 0);
            }
        }
        __syncthreads();
    }

    // ---- phase 5: Y2 -> xl (bf16) + BN partials from f32 accs ----
#pragma unroll
    for (int nt = 0; nt < 8; ++nt) {
        float bv = b2[nt * 16 + m];
        float ss = 0.f, qq = 0.f;
#pragma unroll
        for (int r = 0; r < 4; ++r) {
            int row = wv * 16 + hi * 4 + r;
            float v = acc[nt][r] + bv;
            xl[row * 136 + nt * 16 + m] = f2bf(v);
            if (b * WSZ + row < NN) { ss += v; qq += v * v; }
        }
        sred[(nt * 16 + m) * 16 + wv * 4 + hi] = ss;
        qred[(nt * 16 + m) * 16 + wv * 4 + hi] = qq;
    }
    __syncthreads();

    // coalesced Y2 store + stats reduce
#pragma unroll
    for (int l = 0; l < 4; ++l) {
        int idx = t + l * 256;
        int row = idx >> 4, c = idx & 15;
        int g = b * WSZ + row;
        if (g < NN)
            ((short8*)Y)[g * 16 + c] = *(const short8*)&xl[row * 136 + c * 8];
    }
    if (t < 128) {
        float s = 0.f, q = 0.f;
#pragma unroll
        for (int j = 0; j < 16; ++j) { s += sred[t * 16 + j]; q += qred[t * 16 + j]; }
        atomicAdd(&stats[t], s);
        atomicAdd(&stats[DD + t], q);
    }
}

// ---------------------------------------------------------------------------
// Kernel 3: out = h + relu(Y*scale + shift). Column octet fixed per thread
// across the grid-stride loop -> BN math hoisted; Y read as short8.
// ---------------------------------------------------------------------------
__global__ __launch_bounds__(256) void bn_final_kernel(
    const unsigned short* __restrict__ Y, const float* __restrict__ h,
    const float* __restrict__ gamma, const float* __restrict__ beta,
    const float* __restrict__ stats, float* __restrict__ out)
{
    const float invN = 1.0f / (float)NN;
    int t0 = blockIdx.x * 256 + threadIdx.x;
    int c8 = t0 & 15;
    float sc[8], sh[8];
#pragma unroll
    for (int j = 0; j < 8; ++j) {
        int col = c8 * 8 + j;
        float mu = stats[col] * invN;
        float var = stats[DD + col] * invN - mu * mu;
        float s = rsqrtf(var + BN_EPS) * gamma[col];
        sc[j] = s;
        sh[j] = beta[col] - mu * s;
    }
    const short8* Y8 = (const short8*)Y;
    const float4* H4 = (const float4*)h;
    float4* O4 = (float4*)out;
    const int total = NN * 16;
    const int stride = BN_BLOCKS * 256;
    for (int i = t0; i < total; i += stride) {
        short8 u = Y8[i];
        float4 h0 = H4[2 * i], h1 = H4[2 * i + 1];
        float4 r0, r1;
        r0.x = h0.x + fmaxf(bf2f((unsigned short)u[0]) * sc[0] + sh[0], 0.f);
        r0.y = h0.y + fmaxf(bf2f((unsigned short)u[1]) * sc[1] + sh[1], 0.f);
        r0.z = h0.z + fmaxf(bf2f((unsigned short)u[2]) * sc[2] + sh[2], 0.f);
        r0.w = h0.w + fmaxf(bf2f((unsigned short)u[3]) * sc[3] + sh[3], 0.f);
        r1.x = h1.x + fmaxf(bf2f((unsigned short)u[4]) * sc[4] + sh[4], 0.f);
        r1.y = h1.y + fmaxf(bf2f((unsigned short)u[5]) * sc[5] + sh[5], 0.f);
        r1.z = h1.z + fmaxf(bf2f((unsigned short)u[6]) * sc[6] + sh[6], 0.f);
        r1.w = h1.w + fmaxf(bf2f((unsigned short)u[7]) * sc[7] + sh[7], 0.f);
        O4[2 * i] = r0;
        O4[2 * i + 1] = r1;
    }
}

// ---------------------------------------------------------------------------
extern "C" void kernel_launch(void* const* d_in, const int* in_sizes, int n_in,
                              void* d_out, int out_size, void* d_ws, size_t ws_size,
                              hipStream_t stream)
{
    const float* h     = (const float*)d_in[0];
    const int*   src   = (const int*)d_in[1];
    const int*   dst   = (const int*)d_in[2];
    const float* eps   = (const float*)d_in[3];
    const float* W1    = (const float*)d_in[4];
    const float* b1    = (const float*)d_in[5];
    const float* W2    = (const float*)d_in[6];
    const float* b2    = (const float*)d_in[7];
    const float* gamma = (const float*)d_in[8];
    const float* beta  = (const float*)d_in[9];
    float* out = (float*)d_out;

    char* w = (char*)d_ws;
    size_t o = 0;
    float* stats    = (float*)(w + o); o += 256 * 4;                 // 1024
    int* wcnt       = (int*)(w + o); o += NWINP * 4;                 // 8192
    unsigned short* W1t = (unsigned short*)(w + o); o += (size_t)DD * DD * 2;
    unsigned short* W2t = (unsigned short*)(w + o); o += (size_t)DD * DD * 2;
    int* estage     = (int*)(w + o); o += (size_t)NWIN * CAP * 4;    // 9.6 MB
    unsigned short* xb  = (unsigned short*)(w + o); o += (size_t)NN * DD * 2;  // Y2 only
    unsigned short* hb  = (unsigned short*)(w + o); o += (size_t)NN * DD * 2;
    const int use_hb = (ws_size >= o) ? 1 : 0;  // launch-constant

    // 0. zero window cursors
    hipMemsetAsync(wcnt, 0, NWINP * sizeof(int), stream);

    // 1. fused prep + write-combined window scatter
    prep_scatter_kernel<<<GRID_PS, 256, 0, stream>>>(
        stats, W1, W2, W1t, W2t, h, hb, use_hb, src, dst, wcnt, estage);

    // 2. fused permute + gather + 2-layer MLP + BN stats
    if (use_hb)
        permgather_mlp_kernel<true><<<NWIN, 256, 0, stream>>>(
            h, hb, eps, wcnt, estage, W1t, W2t, b1, b2, xb, stats);
    else
        permgather_mlp_kernel<false><<<NWIN, 256, 0, stream>>>(
            h, hb, eps, wcnt, estage, W1t, W2t, b1, b2, xb, stats);

    // 3. out = h + relu(BN(y2))
    bn_final_kernel<<<BN_BLOCKS, 256, 0, stream>>>(xb, h, gamma, beta, stats, out);
}